// Round 5
// baseline (106.316 us; speedup 1.0000x reference)
//
#include <hip/hip_runtime.h>
#include <hip/hip_bf16.h>
#include <stdint.h>

typedef short bh8 __attribute__((ext_vector_type(8)));
typedef short bh4 __attribute__((ext_vector_type(4)));
typedef float fx4 __attribute__((ext_vector_type(4)));

#define B_ 8
#define S_ 2048
#define E_ 1024
#define HD_ 64

__device__ __forceinline__ short f2bf(float f) {
  unsigned u = __builtin_bit_cast(unsigned, f);
  u = u + 0x7FFFu + ((u >> 16) & 1u);   // RNE
  return (short)(u >> 16);
}

#define GL2LDS16(gp, lp) __builtin_amdgcn_global_load_lds( \
    (const __attribute__((address_space(1))) unsigned int*)(gp), \
    (__attribute__((address_space(3))) unsigned int*)(lp), 16, 0, 0)

// ---------- cast W (3 x [64][1024] f32) -> wc bf16 [192][1024], order K,Q,V ----------
__global__ __launch_bounds__(256) void castw_k(
    const float* __restrict__ wk, const float* __restrict__ wq,
    const float* __restrict__ wv, short* __restrict__ wc) {
  int i = blockIdx.x * 256 + threadIdx.x;
  int wsel = i >> 13;
  int o = (i & 8191) * 8;
  const float* src = (wsel == 0) ? wk : (wsel == 1) ? wq : wv;
  float4 a = *(const float4*)(src + o);
  float4 b = *(const float4*)(src + o + 4);
  bh8 r = { f2bf(a.x), f2bf(a.y), f2bf(a.z), f2bf(a.w),
            f2bf(b.x), f2bf(b.y), f2bf(b.z), f2bf(b.w) };
  *(bh8*)(wc + wsel * (HD_ * E_) + o) = r;
}

// ---------- QKV GEMM, 2-phase pipelined: [16384 x 1024] x [192 x 1024]^T ----------
__global__ __launch_bounds__(256) void qkv_gemm(
    const float* __restrict__ x, const short* __restrict__ wc,
    short* __restrict__ ko, short* __restrict__ qo, short* __restrict__ vt) {
  __shared__ short As[2][32 * 32];
  __shared__ short Bs[2][192 * 32];
  const int tid = threadIdx.x;
  const int w = tid >> 6, l = tid & 63;
  const int c = l & 15, g = l >> 4;
  const int r0 = blockIdx.x * 32;
  const int srow = l >> 2;
  const int scol = (l & 3) * 8;
  const int ar = tid >> 3;
  const int ac = (tid & 7) * 4;

  fx4 acc[2][3];
#pragma unroll
  for (int rt = 0; rt < 2; ++rt)
#pragma unroll
    for (int cc = 0; cc < 3; ++cc) acc[rt][cc] = (fx4){0.f, 0.f, 0.f, 0.f};

  // prologue: stage tile 0
  {
    float4 av = *(const float4*)(x + (size_t)(r0 + ar) * E_ + ac);
    bh4 aw = { f2bf(av.x), f2bf(av.y), f2bf(av.z), f2bf(av.w) };
    *(bh4*)&As[0][ar * 32 + ac] = aw;
#pragma unroll
    for (int p = 0; p < 3; ++p)
      GL2LDS16(wc + (size_t)(16 * (w + 4 * p) + srow) * E_ + scol,
               &Bs[0][(w + 4 * p) * 512]);
  }
  __syncthreads();   // drains glds (vmcnt) + ds_write

  int cur = 0;
  for (int t = 0; t < 32; ++t) {
    const int nxt = cur ^ 1;
    float4 av;
    if (t < 31) {   // issue next-tile loads BEFORE computing current
      const int k0 = (t + 1) * 32;
      av = *(const float4*)(x + (size_t)(r0 + ar) * E_ + k0 + ac);
#pragma unroll
      for (int p = 0; p < 3; ++p)
        GL2LDS16(wc + (size_t)(16 * (w + 4 * p) + srow) * E_ + k0 + scol,
                 &Bs[nxt][(w + 4 * p) * 512]);
    }

    bh8 af[2], bf[3];
    af[0] = *(const bh8*)&As[cur][c * 32 + 8 * g];
    af[1] = *(const bh8*)&As[cur][(16 + c) * 32 + 8 * g];
#pragma unroll
    for (int cc = 0; cc < 3; ++cc)
      bf[cc] = *(const bh8*)&Bs[cur][(16 * (3 * w + cc) + c) * 32 + 8 * g];
#pragma unroll
    for (int rt = 0; rt < 2; ++rt)
#pragma unroll
      for (int cc = 0; cc < 3; ++cc)
        acc[rt][cc] = __builtin_amdgcn_mfma_f32_16x16x32_bf16(af[rt], bf[cc], acc[rt][cc], 0, 0, 0);

    if (t < 31) {
      bh4 aw = { f2bf(av.x), f2bf(av.y), f2bf(av.z), f2bf(av.w) };
      *(bh4*)&As[nxt][ar * 32 + ac] = aw;
    }
    __syncthreads();   // one barrier per K-step: waits glds into Bs[nxt] too
    cur = nxt;
  }

#pragma unroll
  for (int rt = 0; rt < 2; ++rt) {
    const int rbase = r0 + 16 * rt + 4 * g;
#pragma unroll
    for (int cc = 0; cc < 3; ++cc) {
      const int ctg = 3 * w + cc;
      const int n = 16 * ctg + c;
      if (ctg < 4) {
#pragma unroll
        for (int j = 0; j < 4; ++j)
          ko[(size_t)(rbase + j) * HD_ + n] = f2bf(acc[rt][cc][j]);
      } else if (ctg < 8) {
#pragma unroll
        for (int j = 0; j < 4; ++j)
          qo[(size_t)(rbase + j) * HD_ + (n - 64)] = f2bf(acc[rt][cc][j] * 0.125f);
      } else {
        const int hd = n - 128;
        const int bb = rbase >> 11, ss = rbase & (S_ - 1);
        bh4 pk = { f2bf(acc[rt][cc][0]), f2bf(acc[rt][cc][1]),
                   f2bf(acc[rt][cc][2]), f2bf(acc[rt][cc][3]) };
        *(bh4*)&vt[((size_t)(bb * HD_ + hd)) * S_ + ss] = pk;
      }
    }
  }
}

// ---------- split-KV causal flash, 64-key rounds: 1 wave per (q-tile, chunk) ----------
__global__ __launch_bounds__(256, 4) void attn_split(
    const short* __restrict__ qb, const short* __restrict__ kb,
    const short* __restrict__ vt, float* __restrict__ pO,
    float* __restrict__ pm, float* __restrict__ pl) {
  const int tid = threadIdx.x;
  const int w = tid >> 6, l = tid & 63;
  const int c = l & 15, g = l >> 4;
  const int wi = blockIdx.x * 4 + w;           // 0..4607
  const int b = wi / 576;
  const int ci = wi - b * 576;
  int G = 0;
  while (8 * (G + 1) * (G + 2) <= ci) ++G;     // cumulative before group G: 8G(G+1)
  const int off = ci - 8 * G * (G + 1);
  const int qt = 16 * G + off / (G + 1);
  const int ch = off % (G + 1);
  const int kt0 = ch * 16;
  const int kt1 = (ch == G) ? (qt + 1) : (kt0 + 16);

  const short* qp = qb + ((size_t)(b * S_ + qt * 16 + c)) * HD_ + 8 * g;
  bh8 qf0 = *(const bh8*)qp;
  bh8 qf1 = *(const bh8*)(qp + 32);

  fx4 o[4];
  o[0] = o[1] = o[2] = o[3] = (fx4){0.f, 0.f, 0.f, 0.f};
  float m = -1e30f, lsum = 0.f;

  const short* kbase = kb + (size_t)b * S_ * HD_ + (size_t)c * HD_ + 8 * g;
  const short* vbase = vt + ((size_t)(b * HD_ + c)) * S_ + 4 * g;

  for (int rt = kt0; rt < kt1; rt += 4) {       // 64 keys per round
    bh8 kf0[4], kf1[4];
#pragma unroll
    for (int i = 0; i < 4; ++i) {
      const int ld = min(rt + i, qt);           // clamp: masked tiles read valid mem
      const short* kp = kbase + (size_t)ld * (16 * HD_);
      kf0[i] = *(const bh8*)kp;
      kf1[i] = *(const bh8*)(kp + 32);
    }
    fx4 s[4];
#pragma unroll
    for (int i = 0; i < 4; ++i) {
      fx4 z = {0.f, 0.f, 0.f, 0.f};
      z = __builtin_amdgcn_mfma_f32_16x16x32_bf16(kf0[i], qf0, z, 0, 0, 0);
      s[i] = __builtin_amdgcn_mfma_f32_16x16x32_bf16(kf1[i], qf1, z, 0, 0, 0);
    }
    // V loads issued here: overlap the softmax chain (kf regs die above)
    bh4 vf[4][4];
#pragma unroll
    for (int i = 0; i < 4; ++i) {
      const int ld = min(rt + i, qt);
      const short* vp = vbase + ld * 16;
#pragma unroll
      for (int mm = 0; mm < 4; ++mm)
        vf[i][mm] = *(const bh4*)(vp + mm * 16 * S_);
    }
    // causal mask
#pragma unroll
    for (int i = 0; i < 4; ++i) {
      const int st = rt + i;
      if (st > qt) {
        s[i][0] = s[i][1] = s[i][2] = s[i][3] = -1e30f;
      } else if (st == qt) {
#pragma unroll
        for (int j = 0; j < 4; ++j)
          if (4 * g + j > c) s[i][j] = -1e30f;
      }
    }
    // one softmax round per 64 keys
    float tmax = -1e30f;
#pragma unroll
    for (int i = 0; i < 4; ++i)
      tmax = fmaxf(tmax, fmaxf(fmaxf(s[i][0], s[i][1]), fmaxf(s[i][2], s[i][3])));
    tmax = fmaxf(tmax, __shfl_xor(tmax, 16, 64));
    tmax = fmaxf(tmax, __shfl_xor(tmax, 32, 64));
    const float mnew = fmaxf(m, tmax);
    const float scale = __expf(m - mnew);
    float p[4][4];
    float ts = 0.f;
#pragma unroll
    for (int i = 0; i < 4; ++i) {
#pragma unroll
      for (int j = 0; j < 4; ++j) p[i][j] = __expf(s[i][j] - mnew);
      ts += (p[i][0] + p[i][1]) + (p[i][2] + p[i][3]);
    }
    ts += __shfl_xor(ts, 16, 64);
    ts += __shfl_xor(ts, 32, 64);
    lsum = lsum * scale + ts;
    m = mnew;
#pragma unroll
    for (int mm = 0; mm < 4; ++mm) o[mm] *= scale;
#pragma unroll
    for (int i = 0; i < 4; ++i) {
      bh4 pf = { f2bf(p[i][0]), f2bf(p[i][1]), f2bf(p[i][2]), f2bf(p[i][3]) };
#pragma unroll
      for (int mm = 0; mm < 4; ++mm)
        o[mm] = __builtin_amdgcn_mfma_f32_16x16x16bf16_1k(vf[i][mm], pf, o[mm], 0, 0, 0);
    }
  }

  // partial O: [wi][row 16][col 64] f32, unnormalized
#pragma unroll
  for (int mm = 0; mm < 4; ++mm)
    *(fx4*)(pO + (size_t)wi * 1024 + c * 64 + 16 * mm + 4 * g) = o[mm];
  if (g == 0) {
    pm[wi * 16 + c] = m;
    pl[wi * 16 + c] = lsum;
  }
}

// ---------- combine partials: 1 wave per q-tile ----------
__global__ __launch_bounds__(256) void attn_combine(
    const float* __restrict__ pO, const float* __restrict__ pm,
    const float* __restrict__ pl, float* __restrict__ out) {
  const int tid = threadIdx.x;
  const int w = tid >> 6, l = tid & 63;
  const int qi = blockIdx.x * 4 + w;           // 0..1023
  const int b = qi >> 7, qt = qi & 127;
  const int G = qt >> 4;
  const int nch = G + 1;
  const int base = b * 576 + 8 * G * (G + 1) + (qt - 16 * G) * nch;
  const int r = l >> 2, cg = l & 3;

  float M = -1e30f;
  for (int i = 0; i < nch; ++i) M = fmaxf(M, pm[(base + i) * 16 + r]);
  float L = 0.f;
  fx4 a0 = {0.f,0.f,0.f,0.f}, a1 = a0, a2 = a0, a3 = a0;
  for (int i = 0; i < nch; ++i) {
    const float mi = pm[(base + i) * 16 + r];
    const float sc = __expf(mi - M);
    L += pl[(base + i) * 16 + r] * sc;
    const float* po = pO + (size_t)(base + i) * 1024 + r * 64 + cg * 16;
    a0 += sc * *(const fx4*)(po);
    a1 += sc * *(const fx4*)(po + 4);
    a2 += sc * *(const fx4*)(po + 8);
    a3 += sc * *(const fx4*)(po + 12);
  }
  const float inv = 1.0f / L;
  float* op = out + ((size_t)(b * S_ + qt * 16 + r)) * HD_ + cg * 16;
  *(fx4*)(op)      = a0 * inv;
  *(fx4*)(op + 4)  = a1 * inv;
  *(fx4*)(op + 8)  = a2 * inv;
  *(fx4*)(op + 12) = a3 * inv;
}

// ---------- fallback: 1-wave-per-q-tile attention (ws too small) ----------
__global__ __launch_bounds__(256) void attn_k(
    const short* __restrict__ qb, const short* __restrict__ kb,
    const short* __restrict__ vt, float* __restrict__ out) {
  const int tid = threadIdx.x;
  const int w = tid >> 6, l = tid & 63;
  const int c = l & 15, g = l >> 4;
  const int blk = blockIdx.x;
  const int b = blk >> 5, p = blk & 31;
  const int qt = (w == 0) ? 2 * p : (w == 1) ? 2 * p + 1
               : (w == 2) ? 126 - 2 * p : 127 - 2 * p;
  const int q0 = qt * 16;
  const short* qp = qb + ((size_t)(b * S_ + q0 + c)) * HD_ + 8 * g;
  bh8 qf0 = *(const bh8*)qp;
  bh8 qf1 = *(const bh8*)(qp + 32);
  fx4 o[4];
  o[0] = o[1] = o[2] = o[3] = (fx4){0.f, 0.f, 0.f, 0.f};
  float m = -1e30f, lsum = 0.f;
  for (int kt = 0; kt <= qt; ++kt) {
    const short* kp = kb + ((size_t)(b * S_ + kt * 16 + c)) * HD_ + 8 * g;
    bh8 kf0 = *(const bh8*)kp;
    bh8 kf1 = *(const bh8*)(kp + 32);
    fx4 s = {0.f, 0.f, 0.f, 0.f};
    s = __builtin_amdgcn_mfma_f32_16x16x32_bf16(kf0, qf0, s, 0, 0, 0);
    s = __builtin_amdgcn_mfma_f32_16x16x32_bf16(kf1, qf1, s, 0, 0, 0);
    if (kt == qt) {
#pragma unroll
      for (int j = 0; j < 4; ++j)
        if (4 * g + j > c) s[j] = -1e30f;
    }
    float tmax = fmaxf(fmaxf(s[0], s[1]), fmaxf(s[2], s[3]));
    tmax = fmaxf(tmax, __shfl_xor(tmax, 16, 64));
    tmax = fmaxf(tmax, __shfl_xor(tmax, 32, 64));
    const float mnew = fmaxf(m, tmax);
    const float scale = __expf(m - mnew);
    const float p0 = __expf(s[0] - mnew);
    const float p1 = __expf(s[1] - mnew);
    const float p2 = __expf(s[2] - mnew);
    const float p3 = __expf(s[3] - mnew);
    float ts = (p0 + p1) + (p2 + p3);
    ts += __shfl_xor(ts, 16, 64);
    ts += __shfl_xor(ts, 32, 64);
    lsum = lsum * scale + ts;
    m = mnew;
#pragma unroll
    for (int mm = 0; mm < 4; ++mm) o[mm] *= scale;
    bh4 pf = { f2bf(p0), f2bf(p1), f2bf(p2), f2bf(p3) };
    const short* vp = vt + (size_t)(b * HD_ + c) * S_ + kt * 16 + 4 * g;
#pragma unroll
    for (int mm = 0; mm < 4; ++mm) {
      bh4 vf = *(const bh4*)(vp + mm * 16 * S_);
      o[mm] = __builtin_amdgcn_mfma_f32_16x16x16bf16_1k(vf, pf, o[mm], 0, 0, 0);
    }
  }
  const float inv = 1.0f / lsum;
  float* op = out + ((size_t)(b * S_ + q0 + c)) * HD_ + 4 * g;
#pragma unroll
  for (int mm = 0; mm < 4; ++mm) {
    fx4 r = o[mm] * inv;
    *(fx4*)(op + 16 * mm) = r;
  }
}

extern "C" void kernel_launch(void* const* d_in, const int* in_sizes, int n_in,
                              void* d_out, int out_size, void* d_ws, size_t ws_size,
                              hipStream_t stream) {
  const float* x  = (const float*)d_in[0];
  const float* wk = (const float*)d_in[1];
  const float* wq = (const float*)d_in[2];
  const float* wv = (const float*)d_in[3];
  float* out = (float*)d_out;
  char* ws = (char*)d_ws;
  short* wc = (short*)(ws);                          // 384 KB
  short* kb = (short*)(ws + 393216);                 // 2 MB
  short* qb = (short*)(ws + 393216 + 2097152);       // 2 MB
  short* vt = (short*)(ws + 393216 + 2 * 2097152);   // 2 MB
  float* pO = (float*)(ws + 6684672);                // 18.87 MB
  float* pm = (float*)(ws + 25559040);
  float* pl = (float*)(ws + 25853952);
  const size_t need = 26148864;

  castw_k<<<dim3(96), dim3(256), 0, stream>>>(wk, wq, wv, wc);
  qkv_gemm<<<dim3(512), dim3(256), 0, stream>>>(x, wc, kb, qb, vt);
  if (ws_size >= need) {
    attn_split<<<dim3(1152), dim3(256), 0, stream>>>(qb, kb, vt, pO, pm, pl);
    attn_combine<<<dim3(256), dim3(256), 0, stream>>>(pO, pm, pl, out);
  } else {
    attn_k<<<dim3(256), dim3(256), 0, stream>>>(qb, kb, vt, out);
  }
}

// Round 6
// 80.209 us; speedup vs baseline: 1.3255x; 1.3255x over previous
//
#include <hip/hip_runtime.h>
#include <hip/hip_bf16.h>
#include <stdint.h>

typedef short bh8 __attribute__((ext_vector_type(8)));
typedef short bh4 __attribute__((ext_vector_type(4)));
typedef float fx4 __attribute__((ext_vector_type(4)));

#define B_ 8
#define S_ 2048
#define E_ 1024
#define HD_ 64

__device__ __forceinline__ short f2bf(float f) {
  unsigned u = __builtin_bit_cast(unsigned, f);
  u = u + 0x7FFFu + ((u >> 16) & 1u);   // RNE
  return (short)(u >> 16);
}

#define GL2LDS16(gp, lp) __builtin_amdgcn_global_load_lds( \
    (const __attribute__((address_space(1))) unsigned int*)(gp), \
    (__attribute__((address_space(3))) unsigned int*)(lp), 16, 0, 0)

// ---------- cast W (3 x [64][1024] f32) -> wc bf16 [192][1024], order K,Q,V ----------
__global__ __launch_bounds__(256) void castw_k(
    const float* __restrict__ wk, const float* __restrict__ wq,
    const float* __restrict__ wv, short* __restrict__ wc) {
  int i = blockIdx.x * 256 + threadIdx.x;
  int wsel = i >> 13;
  int o = (i & 8191) * 8;
  const float* src = (wsel == 0) ? wk : (wsel == 1) ? wq : wv;
  float4 a = *(const float4*)(src + o);
  float4 b = *(const float4*)(src + o + 4);
  bh8 r = { f2bf(a.x), f2bf(a.y), f2bf(a.z), f2bf(a.w),
            f2bf(b.x), f2bf(b.y), f2bf(b.z), f2bf(b.w) };
  *(bh8*)(wc + wsel * (HD_ * E_) + o) = r;
}

// ---------- QKV GEMM (r3 version: single LDS buffer, 14KB, high block-TLP) ----------
__global__ __launch_bounds__(256) void qkv_gemm(
    const float* __restrict__ x, const short* __restrict__ wc,
    short* __restrict__ ko, short* __restrict__ qo, short* __restrict__ vt) {
  __shared__ short As[32 * 32];
  __shared__ short Bs[192 * 32];
  const int tid = threadIdx.x;
  const int w = tid >> 6, l = tid & 63;
  const int c = l & 15, g = l >> 4;
  const int r0 = blockIdx.x * 32;
  const int srow = l >> 2;
  const int scol = (l & 3) * 8;
  const int ar = tid >> 3;
  const int ac = (tid & 7) * 4;

  fx4 acc[2][3];
#pragma unroll
  for (int rt = 0; rt < 2; ++rt)
#pragma unroll
    for (int cc = 0; cc < 3; ++cc) acc[rt][cc] = (fx4){0.f, 0.f, 0.f, 0.f};

  for (int k0 = 0; k0 < E_; k0 += 32) {
    float4 av = *(const float4*)(x + (size_t)(r0 + ar) * E_ + k0 + ac);
    __syncthreads();
#pragma unroll
    for (int p = 0; p < 3; ++p)
      GL2LDS16(wc + (size_t)(16 * (w + 4 * p) + srow) * E_ + k0 + scol,
               &Bs[(w + 4 * p) * 512]);
    bh4 aw = { f2bf(av.x), f2bf(av.y), f2bf(av.z), f2bf(av.w) };
    *(bh4*)&As[ar * 32 + ac] = aw;
    __syncthreads();

    bh8 af[2], bf[3];
    af[0] = *(const bh8*)&As[c * 32 + 8 * g];
    af[1] = *(const bh8*)&As[(16 + c) * 32 + 8 * g];
#pragma unroll
    for (int cc = 0; cc < 3; ++cc)
      bf[cc] = *(const bh8*)&Bs[(16 * (3 * w + cc) + c) * 32 + 8 * g];
#pragma unroll
    for (int rt = 0; rt < 2; ++rt)
#pragma unroll
      for (int cc = 0; cc < 3; ++cc)
        acc[rt][cc] = __builtin_amdgcn_mfma_f32_16x16x32_bf16(af[rt], bf[cc], acc[rt][cc], 0, 0, 0);
  }

#pragma unroll
  for (int rt = 0; rt < 2; ++rt) {
    const int rbase = r0 + 16 * rt + 4 * g;
#pragma unroll
    for (int cc = 0; cc < 3; ++cc) {
      const int ctg = 3 * w + cc;
      const int n = 16 * ctg + c;
      if (ctg < 4) {
#pragma unroll
        for (int j = 0; j < 4; ++j)
          ko[(size_t)(rbase + j) * HD_ + n] = f2bf(acc[rt][cc][j]);
      } else if (ctg < 8) {
#pragma unroll
        for (int j = 0; j < 4; ++j)
          qo[(size_t)(rbase + j) * HD_ + (n - 64)] = f2bf(acc[rt][cc][j] * 0.125f);
      } else {
        const int hd = n - 128;
        const int bb = rbase >> 11, ss = rbase & (S_ - 1);
        bh4 pk = { f2bf(acc[rt][cc][0]), f2bf(acc[rt][cc][1]),
                   f2bf(acc[rt][cc][2]), f2bf(acc[rt][cc][3]) };
        *(bh4*)&vt[((size_t)(bb * HD_ + hd)) * S_ + ss] = pk;
      }
    }
  }
}

// ---------- fused causal flash: 1 block (8 waves) per (batch, q-tile pair) ----------
// Block handles q-tiles (p, 127-p): each wave takes a contiguous k-chunk of BOTH
// (uniform ~17 k-tiles/wave). Partials merge in LDS; no global combine pass.
__global__ __launch_bounds__(512, 4) void attn_fused(
    const short* __restrict__ qb, const short* __restrict__ kb,
    const short* __restrict__ vt, float* __restrict__ out) {
  __shared__ float pO[2][8][16][68];        // [qsel][wave][row][col] (+4 pad)
  __shared__ float pml[2][2][8][16];        // [qsel][m|l][wave][row]
  const int tid = threadIdx.x;
  const int w = tid >> 6, l = tid & 63;
  const int c = l & 15, g = l >> 4;
  const int b = blockIdx.x >> 6, p = blockIdx.x & 63;

  const short* kbase = kb + (size_t)b * S_ * HD_ + (size_t)c * HD_ + 8 * g;
  const short* vbase = vt + ((size_t)(b * HD_ + c)) * S_ + 4 * g;

  for (int qsel = 0; qsel < 2; ++qsel) {
    const int qt = qsel ? (127 - p) : p;
    const int nt = qt + 1;
    const int cnt = (nt + 7) >> 3;          // k-tiles per wave
    const int start = w * cnt;
    const int end = min(start + cnt, nt);

    fx4 o[4];
    o[0] = o[1] = o[2] = o[3] = (fx4){0.f, 0.f, 0.f, 0.f};
    float m = -1e30f, lsum = 0.f;

    if (start < end) {
      const short* qp = qb + ((size_t)(b * S_ + qt * 16 + c)) * HD_ + 8 * g;
      bh8 qf0 = *(const bh8*)qp;
      bh8 qf1 = *(const bh8*)(qp + 32);

      // prefetch first K tile
      const short* kp = kbase + (size_t)start * (16 * HD_);
      bh8 kc0 = *(const bh8*)kp;
      bh8 kc1 = *(const bh8*)(kp + 32);

      for (int kt = start; kt < end; ++kt) {
        // prefetch next K (dummy reload of current on last iter)
        const int ktn = (kt + 1 < end) ? kt + 1 : kt;
        const short* kpn = kbase + (size_t)ktn * (16 * HD_);
        bh8 kn0 = *(const bh8*)kpn;
        bh8 kn1 = *(const bh8*)(kpn + 32);
        // V issued early: latency hides under QK^T + softmax
        const short* vp = vbase + kt * 16;
        bh4 vf0 = *(const bh4*)vp;
        bh4 vf1 = *(const bh4*)(vp + 16 * S_);
        bh4 vf2 = *(const bh4*)(vp + 32 * S_);
        bh4 vf3 = *(const bh4*)(vp + 48 * S_);

        fx4 s = {0.f, 0.f, 0.f, 0.f};
        s = __builtin_amdgcn_mfma_f32_16x16x32_bf16(kc0, qf0, s, 0, 0, 0);
        s = __builtin_amdgcn_mfma_f32_16x16x32_bf16(kc1, qf1, s, 0, 0, 0);

        if (kt == qt) {                     // diagonal: key (4g+j) > q (c)
#pragma unroll
          for (int j = 0; j < 4; ++j)
            if (4 * g + j > c) s[j] = -1e30f;
        }

        float tmax = fmaxf(fmaxf(s[0], s[1]), fmaxf(s[2], s[3]));
        tmax = fmaxf(tmax, __shfl_xor(tmax, 16, 64));
        tmax = fmaxf(tmax, __shfl_xor(tmax, 32, 64));
        const float mnew = fmaxf(m, tmax);
        const float scale = __expf(m - mnew);
        const float p0 = __expf(s[0] - mnew);
        const float p1 = __expf(s[1] - mnew);
        const float p2 = __expf(s[2] - mnew);
        const float p3 = __expf(s[3] - mnew);
        float ts = (p0 + p1) + (p2 + p3);
        ts += __shfl_xor(ts, 16, 64);
        ts += __shfl_xor(ts, 32, 64);
        lsum = lsum * scale + ts;
        m = mnew;
#pragma unroll
        for (int mm = 0; mm < 4; ++mm) o[mm] *= scale;

        bh4 pf = { f2bf(p0), f2bf(p1), f2bf(p2), f2bf(p3) };
        o[0] = __builtin_amdgcn_mfma_f32_16x16x16bf16_1k(vf0, pf, o[0], 0, 0, 0);
        o[1] = __builtin_amdgcn_mfma_f32_16x16x16bf16_1k(vf1, pf, o[1], 0, 0, 0);
        o[2] = __builtin_amdgcn_mfma_f32_16x16x16bf16_1k(vf2, pf, o[2], 0, 0, 0);
        o[3] = __builtin_amdgcn_mfma_f32_16x16x16bf16_1k(vf3, pf, o[3], 0, 0, 0);

        kc0 = kn0; kc1 = kn1;
      }
    }
    // write partial to LDS (inactive wave: o=0, m=-1e30, l=0 -> weight 0 in merge)
#pragma unroll
    for (int mm = 0; mm < 4; ++mm)
      *(fx4*)&pO[qsel][w][c][16 * mm + 4 * g] = o[mm];
    if (g == 0) {
      pml[qsel][0][w][c] = m;
      pml[qsel][1][w][c] = lsum;
    }
  }

  __syncthreads();

  if (w < 2) {                              // wave 0 -> qa, wave 1 -> qb
    const int qsel = w;
    const int qt = qsel ? (127 - p) : p;
    float M = -1e30f;
#pragma unroll
    for (int i = 0; i < 8; ++i) M = fmaxf(M, pml[qsel][0][i][c]);
    float L = 0.f;
    fx4 a[4];
    a[0] = a[1] = a[2] = a[3] = (fx4){0.f, 0.f, 0.f, 0.f};
#pragma unroll
    for (int i = 0; i < 8; ++i) {
      const float sc = __expf(pml[qsel][0][i][c] - M);
      L += pml[qsel][1][i][c] * sc;
#pragma unroll
      for (int mm = 0; mm < 4; ++mm)
        a[mm] += sc * *(const fx4*)&pO[qsel][i][c][16 * mm + 4 * g];
    }
    const float inv = 1.0f / L;
    float* op = out + ((size_t)(b * S_ + qt * 16 + c)) * HD_ + 4 * g;
#pragma unroll
    for (int mm = 0; mm < 4; ++mm) {
      fx4 r = a[mm] * inv;
      *(fx4*)(op + 16 * mm) = r;
    }
  }
}

extern "C" void kernel_launch(void* const* d_in, const int* in_sizes, int n_in,
                              void* d_out, int out_size, void* d_ws, size_t ws_size,
                              hipStream_t stream) {
  const float* x  = (const float*)d_in[0];
  const float* wk = (const float*)d_in[1];
  const float* wq = (const float*)d_in[2];
  const float* wv = (const float*)d_in[3];
  float* out = (float*)d_out;
  char* ws = (char*)d_ws;
  short* wc = (short*)(ws);                          // 384 KB
  short* kb = (short*)(ws + 393216);                 // 2 MB
  short* qb = (short*)(ws + 393216 + 2097152);       // 2 MB
  short* vt = (short*)(ws + 393216 + 2 * 2097152);   // 2 MB  (total 6.5 MB)

  castw_k<<<dim3(96), dim3(256), 0, stream>>>(wk, wq, wv, wc);
  qkv_gemm<<<dim3(512), dim3(256), 0, stream>>>(x, wc, kb, qb, vt);
  attn_fused<<<dim3(512), dim3(512), 0, stream>>>(qb, kb, vt, out);
}